// Round 3
// baseline (933.532 us; speedup 1.0000x reference)
//
#include <hip/hip_runtime.h>
#include <math.h>

#define HWSZ 4096   // 64*64
#define DIM  64
#define KCW  512
#define NROW 131072 // 32*4096
#define RPB  256    // rows per block (512 threads, 2 threads per row: D-split)

// ws layout (floats): ws[0] = loss accumulator; ws[64 .. 64+512) = c_sq
__global__ void vq_prep_kernel(const float* __restrict__ cw, float* __restrict__ ws) {
    int k = blockIdx.x * blockDim.x + threadIdx.x;
    if (k == 0) ws[0] = 0.f;
    if (k < KCW) {
        float s = 0.f;
        #pragma unroll
        for (int d = 0; d < DIM; ++d) { float c = cw[k * DIM + d]; s = fmaf(c, c, s); }
        ws[64 + k] = s;
    }
}

// Two threads per row, each owning 32 of the 64 dims. Per-thread state is
// x[32] (32 VGPRs) -> no allocator heuristic will spill it. Pair combines the
// partial dot via shfl_xor(1); both lanes then see bit-identical fp32 dist
// sequences (a+b == b+a exactly), so argmin (strict <) matches in both.
__global__ __attribute__((amdgpu_flat_work_group_size(512, 512), amdgpu_waves_per_eu(4, 4)))
void vq_main_kernel(const float* __restrict__ in,
                    const float* __restrict__ cw,
                    float* __restrict__ out,
                    float* __restrict__ ws) {
    const float* __restrict__ c_sq = ws + 64;
    const int t     = threadIdx.x;
    const int half  = t & 1;                    // 0: d in [0,32), 1: d in [32,64)
    const int r     = t >> 1;                   // row within block
    const int row   = blockIdx.x * RPB + r;
    const int b     = row >> 12;
    const int hw    = row & (HWSZ - 1);
    const int dbase = half << 5;

    const float* __restrict__ xin = in + (size_t)b * (DIM * HWSZ) + (size_t)dbase * HWSZ + hw;
    float x[32];
    #pragma unroll
    for (int j = 0; j < 32; ++j) x[j] = xin[(size_t)j * HWSZ];

    float xs = 0.f;
    #pragma unroll
    for (int j = 0; j < 32; ++j) xs = fmaf(x[j], x[j], xs);
    const float x_sq = xs + __shfl_xor(xs, 1, 64);   // same value in both pair lanes

    float best = INFINITY;
    int bestk = 0;
    const float4* __restrict__ cbase = (const float4*)(cw) + half * 8;  // 8 float4 = 32 floats
    #pragma unroll 2
    for (int k = 0; k < KCW; ++k) {
        const float4* __restrict__ c4 = cbase + (size_t)k * (DIM / 4);
        float d0 = 0.f, d1 = 0.f, d2 = 0.f, d3 = 0.f;
        #pragma unroll
        for (int i = 0; i < 8; ++i) {
            float4 c = c4[i];
            d0 = fmaf(x[4 * i + 0], c.x, d0);
            d1 = fmaf(x[4 * i + 1], c.y, d1);
            d2 = fmaf(x[4 * i + 2], c.z, d2);
            d3 = fmaf(x[4 * i + 3], c.w, d3);
        }
        float p  = (d0 + d1) + (d2 + d3);
        float dot = p + __shfl_xor(p, 1, 64);        // identical in both pair lanes
        float dist = (x_sq + c_sq[k]) - 2.f * dot;   // reference rounding order
        if (dist < best) { best = dist; bestk = k; } // strict <: first index wins ties
    }

    // Both pair lanes hold the same bestk. Each writes its 32-dim half.
    const float* __restrict__ q = cw + (size_t)bestk * DIM + dbase;
    float* __restrict__ xout = out + (size_t)b * (DIM * HWSZ) + (size_t)dbase * HWSZ + hw;
    float lsum = 0.f;
    #pragma unroll
    for (int j = 0; j < 32; ++j) {
        float qd = q[j];
        xout[(size_t)j * HWSZ] = qd;
        float diff = qd - x[j];
        lsum = fmaf(diff, diff, lsum);
    }

    if (half == 0) out[(size_t)NROW * DIM + row] = (float)bestk;  // indices chunk

    // wave reduce (covers both halves of each pair) then one atomic per wave
    #pragma unroll
    for (int off = 32; off; off >>= 1) lsum += __shfl_down(lsum, off, 64);
    if ((threadIdx.x & 63) == 0) atomicAdd(ws, lsum);
}

__global__ void vq_finalize_kernel(const float* __restrict__ ws, float* __restrict__ out) {
    // loss = (1 + 0.25) * mean((q - x)^2) over B*H*W*D elements
    out[(size_t)NROW * DIM + NROW] = 1.25f * ws[0] / (float)((size_t)NROW * DIM);
}

extern "C" void kernel_launch(void* const* d_in, const int* in_sizes, int n_in,
                              void* d_out, int out_size, void* d_ws, size_t ws_size,
                              hipStream_t stream) {
    const float* in = (const float*)d_in[0];
    const float* cw = (const float*)d_in[1];
    float* out = (float*)d_out;
    float* ws  = (float*)d_ws;

    hipLaunchKernelGGL(vq_prep_kernel, dim3(2), dim3(256), 0, stream, cw, ws);
    hipLaunchKernelGGL(vq_main_kernel, dim3(NROW / RPB), dim3(512), 0, stream, in, cw, out, ws);
    hipLaunchKernelGGL(vq_finalize_kernel, dim3(1), dim3(1), 0, stream, ws, out);
}

// Round 4
// 173.792 us; speedup vs baseline: 5.3715x; 5.3715x over previous
//
#include <hip/hip_runtime.h>
#include <math.h>

#define HWSZ 4096   // 64*64
#define DIM  64
#define KCW  512
#define NROW 131072 // 32*4096
#define RPB  256    // rows per block (512 threads = 2 k-planes x 256 rows)

// ws layout (floats): ws[0] = loss accumulator; ws[64 .. 64+512) = c_sq
__global__ void vq_prep_kernel(const float* __restrict__ cw, float* __restrict__ ws) {
    int k = blockIdx.x * blockDim.x + threadIdx.x;
    if (k == 0) ws[0] = 0.f;
    if (k < KCW) {
        float s = 0.f;
        #pragma unroll
        for (int d = 0; d < DIM; ++d) { float c = cw[k * DIM + d]; s = fmaf(c, c, s); }
        ws[64 + k] = s;
    }
}

// 512 threads: planes (t>>8) split the K=512 codebook; each thread owns one
// full row x[64] in VGPRs. asm "+v" pins x as asm-defined so the compiler
// cannot rematerialize it by re-loading from `in` inside the k-loop (the
// R1/R2 failure mode). plane via readfirstlane -> codeword addresses are
// provably wave-uniform -> s_load (SMEM pipe) for the codebook stream.
__global__ __attribute__((amdgpu_flat_work_group_size(512, 512), amdgpu_waves_per_eu(4, 4)))
void vq_main_kernel(const float* __restrict__ in,
                    const float* __restrict__ cw,
                    const float* __restrict__ c_sq,     // = ws + 64 (separate arg: keeps s_load eligible)
                    float* __restrict__ loss_acc,       // = ws + 0
                    float* __restrict__ out) {
    __shared__ float sbest[512];
    __shared__ int   sidx[512];

    const int t     = threadIdx.x;
    const int plane = __builtin_amdgcn_readfirstlane(t >> 8);  // wave-uniform in SGPR
    const int r     = t & 255;
    const int row   = blockIdx.x * RPB + r;
    const int b     = row >> 12;
    const int hw    = row & (HWSZ - 1);

    const float* __restrict__ xin = in + (size_t)b * (DIM * HWSZ) + hw;
    float x[DIM];
    #pragma unroll
    for (int j = 0; j < DIM; ++j) x[j] = xin[(size_t)j * HWSZ];
    #pragma unroll
    for (int j = 0; j < DIM; ++j) asm("" : "+v"(x[j]));   // pin in VGPRs; no remat-by-reload

    float x_sq = 0.f;
    #pragma unroll
    for (int j = 0; j < DIM; ++j) x_sq = fmaf(x[j], x[j], x_sq);

    float best = INFINITY;
    int bestk = 0;
    const int k0 = plane << 8;
    #pragma unroll 2
    for (int kk = 0; kk < 256; ++kk) {
        const int k = k0 + kk;                       // uniform -> scalar loads
        const float* c = cw + (size_t)k * DIM;
        float d0 = 0.f, d1 = 0.f, d2 = 0.f, d3 = 0.f;
        #pragma unroll
        for (int i = 0; i < 16; ++i) {
            d0 = fmaf(x[4 * i + 0], c[4 * i + 0], d0);
            d1 = fmaf(x[4 * i + 1], c[4 * i + 1], d1);
            d2 = fmaf(x[4 * i + 2], c[4 * i + 2], d2);
            d3 = fmaf(x[4 * i + 3], c[4 * i + 3], d3);
        }
        float dot = (d0 + d1) + (d2 + d3);
        float dist = (x_sq + c_sq[k]) - 2.f * dot;   // reference rounding order
        if (dist < best) { best = dist; bestk = k; } // strict <: first index wins ties
    }

    sbest[t] = best;
    sidx[t]  = bestk;
    __syncthreads();

    if (t < 256) {
        // plane-0 priority on ties (lower k wins) -> strict < for plane 1
        float b1 = sbest[t + 256];
        int   k1 = sidx[t + 256];
        if (b1 < best) bestk = k1;
        sidx[t] = bestk;
        out[(size_t)NROW * DIM + row] = (float)bestk;   // indices chunk
    }
    __syncthreads();

    const int kw = sidx[r];
    const float* __restrict__ q = cw + (size_t)kw * DIM + plane * 32;
    float* __restrict__ xout = out + (size_t)b * (DIM * HWSZ) + (size_t)(plane * 32) * HWSZ + hw;

    float lsum = 0.f;
    if (plane == 0) {   // wave-uniform branch, static x[] indices in both arms
        #pragma unroll
        for (int i = 0; i < 32; ++i) {
            float qd = q[i];
            xout[(size_t)i * HWSZ] = qd;
            float diff = qd - x[i];
            lsum = fmaf(diff, diff, lsum);
        }
    } else {
        #pragma unroll
        for (int i = 0; i < 32; ++i) {
            float qd = q[i];
            xout[(size_t)i * HWSZ] = qd;
            float diff = qd - x[32 + i];
            lsum = fmaf(diff, diff, lsum);
        }
    }

    // wave-level reduce then one atomic per wave
    #pragma unroll
    for (int off = 32; off; off >>= 1) lsum += __shfl_down(lsum, off, 64);
    if ((t & 63) == 0) atomicAdd(loss_acc, lsum);
}

__global__ void vq_finalize_kernel(const float* __restrict__ ws, float* __restrict__ out) {
    // loss = (1 + 0.25) * mean((q - x)^2) over B*H*W*D elements
    out[(size_t)NROW * DIM + NROW] = 1.25f * ws[0] / (float)((size_t)NROW * DIM);
}

extern "C" void kernel_launch(void* const* d_in, const int* in_sizes, int n_in,
                              void* d_out, int out_size, void* d_ws, size_t ws_size,
                              hipStream_t stream) {
    const float* in = (const float*)d_in[0];
    const float* cw = (const float*)d_in[1];
    float* out = (float*)d_out;
    float* ws  = (float*)d_ws;

    hipLaunchKernelGGL(vq_prep_kernel, dim3(2), dim3(256), 0, stream, cw, ws);
    hipLaunchKernelGGL(vq_main_kernel, dim3(NROW / RPB), dim3(512), 0, stream,
                       in, cw, ws + 64, ws, out);
    hipLaunchKernelGGL(vq_finalize_kernel, dim3(1), dim3(1), 0, stream, ws, out);
}